// Round 6
// baseline (6361.378 us; speedup 1.0000x reference)
//
#include <hip/hip_runtime.h>
#include <math.h>

#define N_NODES 50000
#define N_EDGES 800000

typedef __bf16 bf16;

__device__ __forceinline__ float wave_sum(float v) {
#pragma unroll
  for (int off = 32; off > 0; off >>= 1) v += __shfl_xor(v, off, 64);
  return v;
}

// Read element i of a float tensor whose storage is f32 (flag!=0) or bf16.
__device__ __forceinline__ float load_f(const void* p, size_t i, int f32) {
  return f32 ? ((const float*)p)[i] : (float)((const bf16*)p)[i];
}

// ---------------- dtype + index-width detection (device-side, no host sync) ----
// flags: [0]=x is f32, [1]=edge_attr is f32, [2]=weights are f32, [3]=edge_index is int64
__device__ __forceinline__ int wild_bf16(const void* p) {
  const unsigned short* u = (const unsigned short*)p;
  for (int i = 0; i < 512; ++i) {
    int e = (u[i] >> 7) & 0xFF;
    if (e >= 0xC3) return 1;  // |v| > ~3e20 impossible for real bf16 data here
  }
  return 0;
}

__global__ void k_detect(const void* x, const void* ea, const void* w,
                         const int* ei, int* flags) {
  if (threadIdx.x == 0 && blockIdx.x == 0) {
    flags[0] = wild_bf16(x);
    flags[1] = wild_bf16(ea);
    flags[2] = wild_bf16(w);
    int is64 = 1;
    for (int i = 0; i < 128; ++i) {
      if (ei[2 * i + 1] != 0) { is64 = 0; break; }
    }
    flags[3] = is64;
  }
}

// ---------------- CSR build ----------------

__global__ void k_zero(int* p, int n) {
  int i = blockIdx.x * blockDim.x + threadIdx.x;
  if (i < n) p[i] = 0;
}

__device__ __forceinline__ int load_idx(const int* ei, int e, int is64, int which) {
  size_t idx = (size_t)which * N_EDGES + (size_t)e;
  return is64 ? ei[2 * idx] : ei[idx];
}

__global__ void k_hist(const int* ei, const int* flags, int* counts) {
  int e = blockIdx.x * blockDim.x + threadIdx.x;
  int is64 = flags[3];
  if (e < N_EDGES) {
    int dst = load_idx(ei, e, is64, 1);
    if (dst >= 0 && dst < N_NODES) atomicAdd(&counts[dst], 1);
  }
}

__global__ void k_scan(const int* counts, int* row_ptr, int* cursor) {
  __shared__ int buf[1024];
  __shared__ int carry_s;
  int t = threadIdx.x;
  if (t == 0) carry_s = 0;
  __syncthreads();
  for (int base = 0; base < N_NODES; base += 1024) {
    int v = (base + t < N_NODES) ? counts[base + t] : 0;
    buf[t] = v;
    __syncthreads();
    for (int off = 1; off < 1024; off <<= 1) {
      int x = (t >= off) ? buf[t - off] : 0;
      __syncthreads();
      buf[t] += x;
      __syncthreads();
    }
    int excl = buf[t] - v;
    int carry = carry_s;
    int total = buf[1023];
    if (base + t < N_NODES) {
      row_ptr[base + t] = carry + excl;
      cursor[base + t] = carry + excl;
    }
    __syncthreads();
    if (t == 0) carry_s = carry + total;
    __syncthreads();
  }
  if (t == 0) row_ptr[N_NODES] = carry_s;
}

__global__ void k_scatter(const int* ei, const int* flags, int* cursor,
                          int* csr_src, int* csr_eid) {
  int e = blockIdx.x * blockDim.x + threadIdx.x;
  int is64 = flags[3];
  if (e < N_EDGES) {
    int src = load_idx(ei, e, is64, 0);
    int dst = load_idx(ei, e, is64, 1);
    if (dst >= 0 && dst < N_NODES && src >= 0 && src < N_NODES) {
      int pos = atomicAdd(&cursor[dst], 1);
      if (pos >= 0 && pos < N_EDGES) {
        csr_src[pos] = src;
        csr_eid[pos] = e;
      }
    }
  }
}

// ---------------- direct node GEMM: feat[row] = [q|k|v|s] ----------------
// Reads Wq/Wk/Wv/Ws in native (fan_in, fan_out) layout — no transpose, no prep.
// Each block: 256 cols of 8 consecutive rows.

template <int K, int FO>
__global__ __launch_bounds__(256) void k_gemm_direct(
    const void* __restrict__ A, const int* __restrict__ aflag,
    const void* __restrict__ Wq, const void* __restrict__ bq,
    const void* __restrict__ Wk, const void* __restrict__ bk,
    const void* __restrict__ Wv, const void* __restrict__ bv,
    const void* __restrict__ Ws, const void* __restrict__ bs,
    const int* __restrict__ flags, bf16* __restrict__ feat) {
  constexpr int NT = 4 * FO;
  int af32 = aflag ? aflag[0] : 0;
  int wf32 = flags[2];
  int col = blockIdx.x * 256 + threadIdx.x;
  int m0 = blockIdx.y * 8;
  if (col >= NT) return;
  int sel = col / FO, c = col - sel * FO;
  const void* W = sel == 0 ? Wq : sel == 1 ? Wk : sel == 2 ? Wv : Ws;
  const void* b = sel == 0 ? bq : sel == 1 ? bk : sel == 2 ? bv : bs;
  float bias = load_f(b, c, wf32);
  float acc[8];
#pragma unroll
  for (int r = 0; r < 8; ++r) acc[r] = bias;
  const float* Af = (const float*)A;
  const bf16* Ab = (const bf16*)A;
  for (int k = 0; k < K; ++k) {
    float w = load_f(W, (size_t)k * FO + c, wf32);
#pragma unroll
    for (int r = 0; r < 8; ++r) {
      float a = af32 ? Af[(size_t)(m0 + r) * K + k]
                     : (float)Ab[(size_t)(m0 + r) * K + k];
      acc[r] += a * w;
    }
  }
#pragma unroll
  for (int r = 0; r < 8; ++r)
    feat[(size_t)(m0 + r) * NT + col] = (bf16)acc[r];
}

// ---------------- edge attention: one wave per dst node, direct form --------
// feat row layout (bf16): [ q(FO) | k(FO) | v(FO) | skip(FO) ]
// Per edge: e = ea@We computed inline; alpha = q·(k[src]+e)/sqrt(FO);
// online softmax; agg += a*(v[src]+e); epilogue skip+relu (+ head for FINAL).

template <int FO, bool FINAL>
__global__ __launch_bounds__(256) void k_edge(const bf16* __restrict__ feat,
                                              const void* __restrict__ ea,
                                              const int* __restrict__ flags,
                                              const int* __restrict__ row_ptr,
                                              const int* __restrict__ csr_src,
                                              const int* __restrict__ csr_eid,
                                              const void* __restrict__ We,
                                              bf16* __restrict__ h_out,
                                              const void* __restrict__ Wc,
                                              const void* __restrict__ bc,
                                              float* __restrict__ out) {
  constexpr int FTOT = 4 * FO;
  constexpr int CPL = (FO >= 64) ? FO / 64 : 1;
  int eaf32 = flags[1];
  int wf32 = flags[2];
  int lane = threadIdx.x & 63;
  int node = blockIdx.x * 4 + (threadIdx.x >> 6);  // grid exact: 12500*4 = 50000
  bool act = (FO >= 64) || (lane < FO);
  int cbase = CPL * lane;
  const bf16* fq = feat + (size_t)node * FTOT;

  float q[CPL];
#pragma unroll
  for (int i = 0; i < CPL; ++i) q[i] = act ? (float)fq[cbase + i] : 0.f;

  float m = -INFINITY, ssum = 0.f;
  float vacc[CPL];
#pragma unroll
  for (int i = 0; i < CPL; ++i) vacc[i] = 0.f;

  int start = row_ptr[node], end = row_ptr[node + 1];
  const float scaleA = 1.0f / sqrtf((float)FO);

  for (int p = start; p < end; ++p) {
    int src = csr_src[p];
    int eid = csr_eid[p];
    const bf16* fk = feat + (size_t)src * FTOT + FO;
    float kv[CPL], vv[CPL];
#pragma unroll
    for (int i = 0; i < CPL; ++i) kv[i] = act ? (float)fk[cbase + i] : 0.f;
#pragma unroll
    for (int i = 0; i < CPL; ++i) vv[i] = act ? (float)fk[FO + cbase + i] : 0.f;

    // e = edge_attr[eid] @ We, computed directly: e[c] = sum_j ea[j]*We[j][c]
    float eav = (lane < 32) ? load_f(ea, (size_t)eid * 32 + lane, eaf32) : 0.f;
    float ev[CPL];
#pragma unroll
    for (int i = 0; i < CPL; ++i) ev[i] = 0.f;
#pragma unroll
    for (int j = 0; j < 32; ++j) {
      float eaj = __shfl(eav, j, 64);
      if (act) {
#pragma unroll
        for (int i = 0; i < CPL; ++i)
          ev[i] += eaj * load_f(We, (size_t)j * FO + cbase + i, wf32);
      }
    }

    float part = 0.f;
#pragma unroll
    for (int i = 0; i < CPL; ++i) part += q[i] * (kv[i] + ev[i]);
    float alpha = wave_sum(part) * scaleA;

    float mnew = fmaxf(m, alpha);
    float sc = __expf(m - mnew);     // exp(-inf)=0 on first edge
    float w = __expf(alpha - mnew);
    ssum = ssum * sc + w;
#pragma unroll
    for (int i = 0; i < CPL; ++i) vacc[i] = vacc[i] * sc + w * (vv[i] + ev[i]);
    m = mnew;
  }

  float inv = (ssum > 0.f) ? 1.0f / ssum : 0.f;
  float hv[CPL];
#pragma unroll
  for (int i = 0; i < CPL; ++i) {
    float s = act ? (float)fq[3 * FO + cbase + i] : 0.f;
    hv[i] = fmaxf(vacc[i] * inv + s, 0.f);
  }
  if constexpr (!FINAL) {
    if (act) {
#pragma unroll
      for (int i = 0; i < CPL; ++i) h_out[(size_t)node * FO + cbase + i] = (bf16)hv[i];
    }
  } else {
    // Final head: out[node] = h3 @ Wc + bc, written as FLOAT32 (reference
    // computes in f32 from f32 inputs -> output dtype is f32, not bf16).
    float part2 = (lane < 32) ? hv[0] * load_f(Wc, lane, wf32) : 0.f;
    float s2 = wave_sum(part2);
    if (lane == 0) out[node] = s2 + load_f(bc, 0, wf32);
  }
}

// ---------------- launch ----------------

extern "C" void kernel_launch(void* const* d_in, const int* in_sizes, int n_in,
                              void* d_out, int out_size, void* d_ws, size_t ws_size,
                              hipStream_t stream) {
  (void)in_sizes; (void)n_in; (void)out_size; (void)ws_size;
  const void* x = d_in[0];
  const int* ei = (const int*)d_in[1];
  const void* ea = d_in[2];
  const void *Wq1 = d_in[3], *bq1 = d_in[4], *Wk1 = d_in[5], *bk1 = d_in[6];
  const void *Wv1 = d_in[7], *bv1 = d_in[8], *We1 = d_in[9];
  const void *Ws1 = d_in[10], *bs1 = d_in[11];
  const void *Wq2 = d_in[12], *bq2 = d_in[13], *Wk2 = d_in[14], *bk2 = d_in[15];
  const void *Wv2 = d_in[16], *bv2 = d_in[17], *We2 = d_in[18];
  const void *Ws2 = d_in[19], *bs2 = d_in[20];
  const void *Wq3 = d_in[21], *bq3 = d_in[22], *Wk3 = d_in[23], *bk3 = d_in[24];
  const void *Wv3 = d_in[25], *bv3 = d_in[26], *We3 = d_in[27];
  const void *Ws3 = d_in[28], *bs3 = d_in[29];
  const void *Wc = d_in[30], *bc = d_in[31];

  char* ws = (char*)d_ws;
  size_t off = 0;
  auto alloc = [&](size_t bytes) -> void* {
    void* p = ws + off;
    off = (off + bytes + 255) & ~(size_t)255;
    return p;
  };
  // Total footprint ~71 MB (known-safe: ran without faulting R2-R5).
  bf16* h       = (bf16*)alloc((size_t)N_NODES * 128 * 2);
  int* counts   = (int*)alloc((N_NODES + 1) * 4);
  int* row_ptr  = (int*)alloc((N_NODES + 1) * 4);
  int* cursor   = (int*)alloc((N_NODES + 1) * 4);
  int* csr_src  = (int*)alloc((size_t)N_EDGES * 4);
  int* csr_eid  = (int*)alloc((size_t)N_EDGES * 4);
  int* flags    = (int*)alloc(256);
  bf16* feat    = (bf16*)alloc((size_t)N_NODES * 512 * 2);

  // dtype/index detection + CSR build (shared by all 3 layers)
  k_detect<<<1, 64, 0, stream>>>(x, ea, Wq1, ei, flags);
  k_zero<<<(N_NODES + 256) / 256, 256, 0, stream>>>(counts, N_NODES + 1);
  k_hist<<<(N_EDGES + 255) / 256, 256, 0, stream>>>(ei, flags, counts);
  k_scan<<<1, 1024, 0, stream>>>(counts, row_ptr, cursor);
  k_scatter<<<(N_EDGES + 255) / 256, 256, 0, stream>>>(ei, flags, cursor, csr_src, csr_eid);

  // Layer 1: FI=128, FO=128, NT=512
  {
    dim3 g((512 + 255) / 256, N_NODES / 8);
    k_gemm_direct<128, 128><<<g, 256, 0, stream>>>(x, flags, Wq1, bq1, Wk1, bk1,
                                                   Wv1, bv1, Ws1, bs1, flags, feat);
  }
  k_edge<128, false><<<N_NODES / 4, 256, 0, stream>>>(feat, ea, flags, row_ptr, csr_src,
                                                      csr_eid, We1, h, nullptr, nullptr, nullptr);

  // Layer 2: FI=128, FO=64, NT=256
  {
    dim3 g(1, N_NODES / 8);
    k_gemm_direct<128, 64><<<g, 256, 0, stream>>>(h, nullptr, Wq2, bq2, Wk2, bk2,
                                                  Wv2, bv2, Ws2, bs2, flags, feat);
  }
  k_edge<64, false><<<N_NODES / 4, 256, 0, stream>>>(feat, ea, flags, row_ptr, csr_src,
                                                     csr_eid, We2, h, nullptr, nullptr, nullptr);

  // Layer 3: FI=64, FO=32, NT=128
  {
    dim3 g(1, N_NODES / 8);
    k_gemm_direct<64, 32><<<g, 256, 0, stream>>>(h, nullptr, Wq3, bq3, Wk3, bk3,
                                                 Wv3, bv3, Ws3, bs3, flags, feat);
  }
  k_edge<32, true><<<N_NODES / 4, 256, 0, stream>>>(feat, ea, flags, row_ptr, csr_src,
                                                    csr_eid, We3, nullptr, Wc, bc, (float*)d_out);
}

// Round 7
// 1277.187 us; speedup vs baseline: 4.9808x; 4.9808x over previous
//
#include <hip/hip_runtime.h>
#include <math.h>

#define N_NODES 50000
#define N_EDGES 800000

typedef __bf16 bf16;

__device__ __forceinline__ float wave_sum(float v) {
#pragma unroll
  for (int off = 32; off > 0; off >>= 1) v += __shfl_xor(v, off, 64);
  return v;
}

// ---------------- edge-index width detection (int64 vs int32, device-side) ----
__global__ void k_detect(const int* ei, int* flags) {
  if (threadIdx.x == 0 && blockIdx.x == 0) {
    int is64 = 1;
    for (int i = 0; i < 128; ++i) {
      if (ei[2 * i + 1] != 0) { is64 = 0; break; }
    }
    flags[0] = is64;
  }
}

__device__ __forceinline__ int load_idx(const int* ei, int e, int is64, int which) {
  size_t idx = (size_t)which * N_EDGES + (size_t)e;
  return is64 ? ei[2 * idx] : ei[idx];
}

// ---------------- CSR build ----------------

__global__ void k_zero(int* p, int n) {
  int i = blockIdx.x * blockDim.x + threadIdx.x;
  if (i < n) p[i] = 0;
}

__global__ void k_hist(const int* ei, const int* flags, int* counts) {
  int e = blockIdx.x * blockDim.x + threadIdx.x;
  int is64 = flags[0];
  if (e < N_EDGES) {
    int dst = load_idx(ei, e, is64, 1);
    if (dst >= 0 && dst < N_NODES) atomicAdd(&counts[dst], 1);
  }
}

__global__ void k_scan(const int* counts, int* row_ptr, int* cursor) {
  __shared__ int buf[1024];
  __shared__ int carry_s;
  int t = threadIdx.x;
  if (t == 0) carry_s = 0;
  __syncthreads();
  for (int base = 0; base < N_NODES; base += 1024) {
    int v = (base + t < N_NODES) ? counts[base + t] : 0;
    buf[t] = v;
    __syncthreads();
    for (int off = 1; off < 1024; off <<= 1) {
      int x = (t >= off) ? buf[t - off] : 0;
      __syncthreads();
      buf[t] += x;
      __syncthreads();
    }
    int excl = buf[t] - v;
    int carry = carry_s;
    int total = buf[1023];
    if (base + t < N_NODES) {
      row_ptr[base + t] = carry + excl;
      cursor[base + t] = carry + excl;
    }
    __syncthreads();
    if (t == 0) carry_s = carry + total;
    __syncthreads();
  }
  if (t == 0) row_ptr[N_NODES] = carry_s;
}

__global__ void k_scatter(const int* ei, const int* flags, int* cursor,
                          int* csr_src, int* csr_eid) {
  int e = blockIdx.x * blockDim.x + threadIdx.x;
  int is64 = flags[0];
  if (e < N_EDGES) {
    int src = load_idx(ei, e, is64, 0);
    int dst = load_idx(ei, e, is64, 1);
    if (dst >= 0 && dst < N_NODES && src >= 0 && src < N_NODES) {
      int pos = atomicAdd(&cursor[dst], 1);
      if (pos >= 0 && pos < N_EDGES) {
        csr_src[pos] = src;
        csr_eid[pos] = e;
      }
    }
  }
}

// ---------------- prep: folded qe weights ----------------
// Wqe[k][j] = sum_c Wq[k][c] * We[j][c]   (j<32), bqe[j] = sum_c bq[c]*We[j][c]

template <int FI, int FO>
__global__ void k_prep(const float* __restrict__ Wq, const float* __restrict__ bq,
                       const float* __restrict__ We,
                       float* __restrict__ Wqe, float* __restrict__ bqe) {
  int j = blockIdx.x;    // 0..31
  int k = threadIdx.x;   // 0..FI-1
  float acc = 0.f;
  for (int c = 0; c < FO; ++c) acc += Wq[(size_t)k * FO + c] * We[(size_t)j * FO + c];
  Wqe[(size_t)k * 32 + j] = acc;
  if (k == 0) {
    float b = 0.f;
    for (int c = 0; c < FO; ++c) b += bq[c] * We[(size_t)j * FO + c];
    bqe[j] = b;
  }
}

// ---------------- node GEMM: feat row = [ q | kv-interleaved | s | qe ] -----
// feat col layout: q[c]->c ; k[c]->FO+(c/CPL)*2CPL+(c%CPL) ; v[c]->same+CPL ;
// s[c]->3FO+c ; qe[j]->4FO+j.  8 rows per block-y, 256 cols per block-x.

template <int K, int FO, bool AF32>
__global__ __launch_bounds__(256) void k_gemm(
    const void* __restrict__ A,
    const float* __restrict__ Wq, const float* __restrict__ bq,
    const float* __restrict__ Wk, const float* __restrict__ bk,
    const float* __restrict__ Wv, const float* __restrict__ bv,
    const float* __restrict__ Ws, const float* __restrict__ bs,
    const float* __restrict__ Wqe, const float* __restrict__ bqe,
    bf16* __restrict__ feat) {
  constexpr int CPL = (FO >= 64) ? FO / 64 : 1;
  constexpr int NT = 4 * FO + 32;
  int col = blockIdx.x * 256 + threadIdx.x;
  int m0 = blockIdx.y * 8;
  if (col >= NT) return;
  const float* Wp;
  int stride, cc, pos;
  float bias;
  if (col < 4 * FO) {
    int sel = col / FO, c = col - sel * FO;
    Wp = sel == 0 ? Wq : sel == 1 ? Wk : sel == 2 ? Wv : Ws;
    bias = (sel == 0 ? bq : sel == 1 ? bk : sel == 2 ? bv : bs)[c];
    stride = FO;
    cc = c;
    if (sel == 0) pos = c;
    else if (sel == 3) pos = 3 * FO + c;
    else {
      int g = c / CPL, o = c - g * CPL;
      pos = FO + g * 2 * CPL + (sel == 2 ? CPL : 0) + o;
    }
  } else {
    int j = col - 4 * FO;
    Wp = Wqe; stride = 32; cc = j; bias = bqe[j]; pos = col;
  }
  float acc[8];
#pragma unroll
  for (int r = 0; r < 8; ++r) acc[r] = bias;
  for (int k = 0; k < K; ++k) {
    float w = Wp[(size_t)k * stride + cc];
#pragma unroll
    for (int r = 0; r < 8; ++r) {
      float a = AF32 ? ((const float*)A)[(size_t)(m0 + r) * K + k]
                     : (float)((const bf16*)A)[(size_t)(m0 + r) * K + k];
      acc[r] += a * w;
    }
  }
#pragma unroll
  for (int r = 0; r < 8; ++r)
    feat[(size_t)(m0 + r) * NT + pos] = (bf16)acc[r];
}

// ---------------- edge attention: one wave per dst node ----------------
// Folded form: alpha = (q.k_src + qe.ea)/sqrt(FO); agg = (vacc + wacc@We)/ssum.

template <int FO, bool FINAL>
__global__ __launch_bounds__(256) void k_edge(const bf16* __restrict__ feat,
                                              const float* __restrict__ ea,
                                              const int* __restrict__ row_ptr,
                                              const int* __restrict__ csr_src,
                                              const int* __restrict__ csr_eid,
                                              const float* __restrict__ We,
                                              bf16* __restrict__ h_out,
                                              const float* __restrict__ Wc,
                                              const float* __restrict__ bc,
                                              float* __restrict__ out) {
  constexpr int FTOT = 4 * FO + 32;
  constexpr int CPL = (FO >= 64) ? FO / 64 : 1;
  int lane = threadIdx.x & 63;
  int node = blockIdx.x * 4 + (threadIdx.x >> 6);  // grid exact: 12500*4 = 50000
  bool act = (FO >= 64) || (lane < FO);
  int cbase = CPL * lane;
  const bf16* fq = feat + (size_t)node * FTOT;

  float q[CPL];
#pragma unroll
  for (int i = 0; i < CPL; ++i) q[i] = act ? (float)fq[cbase + i] : 0.f;
  float qe = (lane < 32) ? (float)fq[4 * FO + lane] : 0.f;

  float m = -INFINITY, ssum = 0.f, wacc = 0.f;
  float vacc[CPL];
#pragma unroll
  for (int i = 0; i < CPL; ++i) vacc[i] = 0.f;

  int start = row_ptr[node], end = row_ptr[node + 1];
  const float scaleA = 1.0f / sqrtf((float)FO);

  auto gather = [&](int src, int eid, float* kf, float* vf, float& eav) {
    const bf16* base = feat + (size_t)src * FTOT + FO + 2 * CPL * lane;
    if constexpr (CPL == 2) {
      uint2 raw = *(const uint2*)base;          // {k0,k1,v0,v1} 8B coalesced
      bf16 t[4]; *(uint2*)t = raw;
      kf[0] = t[0]; kf[1] = t[1]; vf[0] = t[2]; vf[1] = t[3];
    } else {
      unsigned raw = *(const unsigned*)base;    // {k,v} 4B
      bf16 t[2]; *(unsigned*)t = raw;
      kf[0] = t[0]; vf[0] = t[1];
    }
    if (!act) {                                  // folds away for FO>=64
#pragma unroll
      for (int i = 0; i < CPL; ++i) { kf[i] = 0.f; vf[i] = 0.f; }
    }
    eav = (lane < 32) ? ea[(size_t)eid * 32 + lane] : 0.f;
  };

  auto update = [&](const float* kf, const float* vf, float eav) {
    float part = qe * eav;
#pragma unroll
    for (int i = 0; i < CPL; ++i) part += q[i] * kf[i];
    float alpha = wave_sum(part) * scaleA;
    float mnew = fmaxf(m, alpha);
    float sc = __expf(m - mnew);   // exp(-inf)=0 on first edge
    float w = __expf(alpha - mnew);
    ssum = ssum * sc + w;
#pragma unroll
    for (int i = 0; i < CPL; ++i) vacc[i] = vacc[i] * sc + w * vf[i];
    wacc = wacc * sc + w * eav;
    m = mnew;
  };

  int p = start;
  for (; p + 4 <= end; p += 4) {
    int srcs[4], eids[4];
#pragma unroll
    for (int u = 0; u < 4; ++u) { srcs[u] = csr_src[p + u]; eids[u] = csr_eid[p + u]; }
    float kf[4][CPL], vf[4][CPL], eav[4];
#pragma unroll
    for (int u = 0; u < 4; ++u) gather(srcs[u], eids[u], kf[u], vf[u], eav[u]);
#pragma unroll
    for (int u = 0; u < 4; ++u) update(kf[u], vf[u], eav[u]);
  }
  for (; p < end; ++p) {
    float kf[CPL], vf[CPL], eav;
    gather(csr_src[p], csr_eid[p], kf, vf, eav);
    update(kf, vf, eav);
  }

  float inv = (ssum > 0.f) ? 1.0f / ssum : 0.f;
  float agg[CPL];
#pragma unroll
  for (int i = 0; i < CPL; ++i) agg[i] = vacc[i];
  // fold edge-attr contribution: agg[c] += sum_j wacc[j] * We[j][c]
#pragma unroll
  for (int j = 0; j < 32; ++j) {
    float wj = __shfl(wacc, j, 64);
    if (act) {
#pragma unroll
      for (int i = 0; i < CPL; ++i) agg[i] += wj * We[(size_t)j * FO + cbase + i];
    }
  }
  float hv[CPL];
#pragma unroll
  for (int i = 0; i < CPL; ++i) {
    float s = act ? (float)fq[3 * FO + cbase + i] : 0.f;
    hv[i] = fmaxf(agg[i] * inv + s, 0.f);
  }
  if constexpr (!FINAL) {
    if (act) {
#pragma unroll
      for (int i = 0; i < CPL; ++i) h_out[(size_t)node * FO + cbase + i] = (bf16)hv[i];
    }
  } else {
    float part2 = (lane < 32) ? hv[0] * Wc[lane] : 0.f;
    float s2 = wave_sum(part2);
    if (lane == 0) out[node] = s2 + bc[0];   // f32 output
  }
}

// ---------------- launch ----------------

extern "C" void kernel_launch(void* const* d_in, const int* in_sizes, int n_in,
                              void* d_out, int out_size, void* d_ws, size_t ws_size,
                              hipStream_t stream) {
  (void)in_sizes; (void)n_in; (void)out_size; (void)ws_size;
  const float* x = (const float*)d_in[0];
  const int* ei = (const int*)d_in[1];
  const float* ea = (const float*)d_in[2];
  const float *Wq1 = (const float*)d_in[3], *bq1 = (const float*)d_in[4];
  const float *Wk1 = (const float*)d_in[5], *bk1 = (const float*)d_in[6];
  const float *Wv1 = (const float*)d_in[7], *bv1 = (const float*)d_in[8];
  const float *We1 = (const float*)d_in[9];
  const float *Ws1 = (const float*)d_in[10], *bs1 = (const float*)d_in[11];
  const float *Wq2 = (const float*)d_in[12], *bq2 = (const float*)d_in[13];
  const float *Wk2 = (const float*)d_in[14], *bk2 = (const float*)d_in[15];
  const float *Wv2 = (const float*)d_in[16], *bv2 = (const float*)d_in[17];
  const float *We2 = (const float*)d_in[18];
  const float *Ws2 = (const float*)d_in[19], *bs2 = (const float*)d_in[20];
  const float *Wq3 = (const float*)d_in[21], *bq3 = (const float*)d_in[22];
  const float *Wk3 = (const float*)d_in[23], *bk3 = (const float*)d_in[24];
  const float *Wv3 = (const float*)d_in[25], *bv3 = (const float*)d_in[26];
  const float *We3 = (const float*)d_in[27];
  const float *Ws3 = (const float*)d_in[28], *bs3 = (const float*)d_in[29];
  const float *Wc = (const float*)d_in[30], *bc = (const float*)d_in[31];

  char* ws = (char*)d_ws;
  size_t off = 0;
  auto alloc = [&](size_t bytes) -> void* {
    void* p = ws + off;
    off = (off + bytes + 255) & ~(size_t)255;
    return p;
  };
  // Total ~74.4 MB (same as the known-safe R6 plan).
  bf16* h       = (bf16*)alloc((size_t)N_NODES * 128 * 2);
  int* counts   = (int*)alloc((N_NODES + 1) * 4);
  int* row_ptr  = (int*)alloc((N_NODES + 1) * 4);
  int* cursor   = (int*)alloc((N_NODES + 1) * 4);
  int* csr_src  = (int*)alloc((size_t)N_EDGES * 4);
  int* csr_eid  = (int*)alloc((size_t)N_EDGES * 4);
  int* flags    = (int*)alloc(256);
  float* Wqe    = (float*)alloc(128 * 32 * 4);
  float* bqe    = (float*)alloc(32 * 4);
  bf16* feat    = (bf16*)alloc((size_t)N_NODES * 544 * 2);

  // index-width detection + CSR build (shared by all 3 layers)
  k_detect<<<1, 1, 0, stream>>>(ei, flags);
  k_zero<<<(N_NODES + 256) / 256, 256, 0, stream>>>(counts, N_NODES + 1);
  k_hist<<<(N_EDGES + 255) / 256, 256, 0, stream>>>(ei, flags, counts);
  k_scan<<<1, 1024, 0, stream>>>(counts, row_ptr, cursor);
  k_scatter<<<(N_EDGES + 255) / 256, 256, 0, stream>>>(ei, flags, cursor, csr_src, csr_eid);

  // Layer 1: FI=128, FO=128, NT=544
  k_prep<128, 128><<<32, 128, 0, stream>>>(Wq1, bq1, We1, Wqe, bqe);
  {
    dim3 g(3, N_NODES / 8);
    k_gemm<128, 128, true><<<g, 256, 0, stream>>>(x, Wq1, bq1, Wk1, bk1, Wv1, bv1,
                                                  Ws1, bs1, Wqe, bqe, feat);
  }
  k_edge<128, false><<<N_NODES / 4, 256, 0, stream>>>(feat, ea, row_ptr, csr_src, csr_eid,
                                                      We1, h, nullptr, nullptr, nullptr);

  // Layer 2: FI=128, FO=64, NT=288
  k_prep<128, 64><<<32, 128, 0, stream>>>(Wq2, bq2, We2, Wqe, bqe);
  {
    dim3 g(2, N_NODES / 8);
    k_gemm<128, 64, false><<<g, 256, 0, stream>>>(h, Wq2, bq2, Wk2, bk2, Wv2, bv2,
                                                  Ws2, bs2, Wqe, bqe, feat);
  }
  k_edge<64, false><<<N_NODES / 4, 256, 0, stream>>>(feat, ea, row_ptr, csr_src, csr_eid,
                                                     We2, h, nullptr, nullptr, nullptr);

  // Layer 3: FI=64, FO=32, NT=160
  k_prep<64, 32><<<32, 64, 0, stream>>>(Wq3, bq3, We3, Wqe, bqe);
  {
    dim3 g(1, N_NODES / 8);
    k_gemm<64, 32, false><<<g, 256, 0, stream>>>(h, Wq3, bq3, Wk3, bk3, Wv3, bv3,
                                                 Ws3, bs3, Wqe, bqe, feat);
  }
  k_edge<32, true><<<N_NODES / 4, 256, 0, stream>>>(feat, ea, row_ptr, csr_src, csr_eid,
                                                    We3, nullptr, Wc, bc, (float*)d_out);
}

// Round 8
// 886.093 us; speedup vs baseline: 7.1791x; 1.4414x over previous
//
#include <hip/hip_runtime.h>
#include <math.h>

#define N_NODES 50000
#define N_EDGES 800000

typedef __bf16 bf16;
typedef __bf16 bf16x8 __attribute__((ext_vector_type(8)));
typedef float f32x4 __attribute__((ext_vector_type(4)));

__device__ __forceinline__ float wave_sum(float v) {
#pragma unroll
  for (int off = 32; off > 0; off >>= 1) v += __shfl_xor(v, off, 64);
  return v;
}

// ---------------- edge-index width detection (int64 vs int32, device-side) ----
__global__ void k_detect(const int* ei, int* flags) {
  if (threadIdx.x == 0 && blockIdx.x == 0) {
    int is64 = 1;
    for (int i = 0; i < 128; ++i) {
      if (ei[2 * i + 1] != 0) { is64 = 0; break; }
    }
    flags[0] = is64;
  }
}

__device__ __forceinline__ int load_idx(const int* ei, int e, int is64, int which) {
  size_t idx = (size_t)which * N_EDGES + (size_t)e;
  return is64 ? ei[2 * idx] : ei[idx];
}

// ---------------- CSR build ----------------

__global__ void k_zero(int* p, int n) {
  int i = blockIdx.x * blockDim.x + threadIdx.x;
  if (i < n) p[i] = 0;
}

__global__ void k_hist(const int* ei, const int* flags, int* counts) {
  int e = blockIdx.x * blockDim.x + threadIdx.x;
  int is64 = flags[0];
  if (e < N_EDGES) {
    int dst = load_idx(ei, e, is64, 1);
    if (dst >= 0 && dst < N_NODES) atomicAdd(&counts[dst], 1);
  }
}

__global__ void k_scan(const int* counts, int* row_ptr, int* cursor) {
  __shared__ int buf[1024];
  __shared__ int carry_s;
  int t = threadIdx.x;
  if (t == 0) carry_s = 0;
  __syncthreads();
  for (int base = 0; base < N_NODES; base += 1024) {
    int v = (base + t < N_NODES) ? counts[base + t] : 0;
    buf[t] = v;
    __syncthreads();
    for (int off = 1; off < 1024; off <<= 1) {
      int x = (t >= off) ? buf[t - off] : 0;
      __syncthreads();
      buf[t] += x;
      __syncthreads();
    }
    int excl = buf[t] - v;
    int carry = carry_s;
    int total = buf[1023];
    if (base + t < N_NODES) {
      row_ptr[base + t] = carry + excl;
      cursor[base + t] = carry + excl;
    }
    __syncthreads();
    if (t == 0) carry_s = carry + total;
    __syncthreads();
  }
  if (t == 0) row_ptr[N_NODES] = carry_s;
}

__global__ void k_scatter(const int* ei, const int* flags, int* cursor,
                          int* csr_src, int* csr_eid) {
  int e = blockIdx.x * blockDim.x + threadIdx.x;
  int is64 = flags[0];
  if (e < N_EDGES) {
    int src = load_idx(ei, e, is64, 0);
    int dst = load_idx(ei, e, is64, 1);
    if (dst >= 0 && dst < N_NODES && src >= 0 && src < N_NODES) {
      int pos = atomicAdd(&cursor[dst], 1);
      if (pos >= 0 && pos < N_EDGES) {
        csr_src[pos] = src;
        csr_eid[pos] = e;
      }
    }
  }
}

// ---------------- weight prep: Wt[n][k] = combined^T (bf16), bias[n] (f32) ----
// Combined columns n: [ q(FO) | k(FO) | v(FO) | s(FO) | qe(32) ],
// qe col j: Wt[4FO+j][k] = sum_c Wq[k][c]*We[j][c]; bias = bq@We[j].

template <int FI, int FO>
__global__ void k_prep(const float* __restrict__ Wq, const float* __restrict__ bq,
                       const float* __restrict__ Wk, const float* __restrict__ bk,
                       const float* __restrict__ Wv, const float* __restrict__ bv,
                       const float* __restrict__ We,
                       const float* __restrict__ Ws, const float* __restrict__ bs,
                       bf16* __restrict__ Wt, float* __restrict__ bias) {
  int n = blockIdx.x;    // 0..NT-1
  int k = threadIdx.x;   // 0..FI-1
  if (n < 4 * FO) {
    int sel = n / FO, c = n - sel * FO;
    const float* W = sel == 0 ? Wq : sel == 1 ? Wk : sel == 2 ? Wv : Ws;
    Wt[(size_t)n * FI + k] = (bf16)W[(size_t)k * FO + c];
    if (k == 0) bias[n] = (sel == 0 ? bq : sel == 1 ? bk : sel == 2 ? bv : bs)[c];
  } else {
    int j = n - 4 * FO;
    float acc = 0.f;
    for (int c = 0; c < FO; ++c) acc += Wq[(size_t)k * FO + c] * We[(size_t)j * FO + c];
    Wt[(size_t)n * FI + k] = (bf16)acc;
    if (k == 0) {
      float b = 0.f;
      for (int c = 0; c < FO; ++c) b += bq[c] * We[(size_t)j * FO + c];
      bias[n] = b;
    }
  }
}

// ---------------- MFMA node GEMM -> interleaved feat ----------------
// feat col layout: q[c]->c ; k[c]->FO+(c/CPL)*2CPL+(c%CPL) ; v[c]->same+CPL ;
// s[c]->3FO+c ; qe[j]->4FO+j.
// MFMA 16x16x32 bf16; wave = 16 rows x 64 cols; block = 4 waves = 64 rows.
// C/D mapping (verified R3<->R4 bit-identical vs naive): col=lane&15, row=quad*4+reg.

template <int K, int FO, bool AF32>
__global__ __launch_bounds__(256) void k_gemm_mfma(const void* __restrict__ A,
                                                   const bf16* __restrict__ Wt,
                                                   const float* __restrict__ bias,
                                                   bf16* __restrict__ feat) {
  constexpr int CPL = (FO >= 64) ? FO / 64 : 1;
  constexpr int NT = 4 * FO + 32;
  int lane = threadIdx.x & 63;
  int wave = threadIdx.x >> 6;
  int m0 = blockIdx.y * 64 + wave * 16;
  if (m0 >= N_NODES) return;   // N_NODES % 16 == 0: strips all-or-nothing
  int c0 = blockIdx.x * 64;
  int half = lane & 15;
  int quad = lane >> 4;
  f32x4 acc[4] = {};
#pragma unroll
  for (int kb = 0; kb < K; kb += 32) {
    size_t aoff = (size_t)(m0 + half) * K + kb + quad * 8;
    bf16x8 a;
    if constexpr (AF32) {
      const float* Af = (const float*)A;
      f32x4 lo = *(const f32x4*)(Af + aoff);
      f32x4 hi = *(const f32x4*)(Af + aoff + 4);
#pragma unroll
      for (int j = 0; j < 4; ++j) { a[j] = (bf16)lo[j]; a[4 + j] = (bf16)hi[j]; }
    } else {
      a = *(const bf16x8*)((const bf16*)A + aoff);
    }
#pragma unroll
    for (int f = 0; f < 4; ++f) {
      int cb = c0 + f * 16;
      if (cb < NT) {
        bf16x8 b = *(const bf16x8*)(Wt + (size_t)(cb + half) * K + kb + quad * 8);
        acc[f] = __builtin_amdgcn_mfma_f32_16x16x32_bf16(a, b, acc[f], 0, 0, 0);
      }
    }
  }
#pragma unroll
  for (int f = 0; f < 4; ++f) {
    int cb = c0 + f * 16;
    if (cb < NT) {
      int col = cb + half;
      int pos;
      if (col < 4 * FO) {
        int sel = col / FO, c = col - sel * FO;
        if (sel == 0) pos = c;
        else if (sel == 3) pos = 3 * FO + c;
        else {
          int g = c / CPL, o = c - g * CPL;
          pos = FO + g * 2 * CPL + (sel == 2 ? CPL : 0) + o;
        }
      } else {
        pos = col;
      }
      float bv = bias[col];
#pragma unroll
      for (int r = 0; r < 4; ++r) {
        int row = m0 + quad * 4 + r;
        feat[(size_t)row * NT + pos] = (bf16)(acc[f][r] + bv);
      }
    }
  }
}

// ---------------- edge attention: one wave per dst node ----------------
// Folded form: alpha = (q.k_src + qe.ea)/sqrt(FO); agg = (vacc + wacc@We)/ssum.

template <int FO, bool FINAL>
__global__ __launch_bounds__(256) void k_edge(const bf16* __restrict__ feat,
                                              const float* __restrict__ ea,
                                              const int* __restrict__ row_ptr,
                                              const int* __restrict__ csr_src,
                                              const int* __restrict__ csr_eid,
                                              const float* __restrict__ We,
                                              bf16* __restrict__ h_out,
                                              const float* __restrict__ Wc,
                                              const float* __restrict__ bc,
                                              float* __restrict__ out) {
  constexpr int FTOT = 4 * FO + 32;
  constexpr int CPL = (FO >= 64) ? FO / 64 : 1;
  int lane = threadIdx.x & 63;
  int node = blockIdx.x * 4 + (threadIdx.x >> 6);  // grid exact: 12500*4 = 50000
  bool act = (FO >= 64) || (lane < FO);
  int cbase = CPL * lane;
  const bf16* fq = feat + (size_t)node * FTOT;

  float q[CPL];
#pragma unroll
  for (int i = 0; i < CPL; ++i) q[i] = act ? (float)fq[cbase + i] : 0.f;
  float qe = (lane < 32) ? (float)fq[4 * FO + lane] : 0.f;

  float m = -INFINITY, ssum = 0.f, wacc = 0.f;
  float vacc[CPL];
#pragma unroll
  for (int i = 0; i < CPL; ++i) vacc[i] = 0.f;

  int start = row_ptr[node], end = row_ptr[node + 1];
  const float scaleA = 1.0f / sqrtf((float)FO);

  auto gather = [&](int src, int eid, float* kf, float* vf, float& eav) {
    const bf16* base = feat + (size_t)src * FTOT + FO + 2 * CPL * lane;
    if constexpr (CPL == 2) {
      uint2 raw = *(const uint2*)base;          // {k0,k1,v0,v1} 8B coalesced
      bf16 t[4]; *(uint2*)t = raw;
      kf[0] = t[0]; kf[1] = t[1]; vf[0] = t[2]; vf[1] = t[3];
    } else {
      unsigned raw = *(const unsigned*)base;    // {k,v} 4B
      bf16 t[2]; *(unsigned*)t = raw;
      kf[0] = t[0]; vf[0] = t[1];
    }
    if (!act) {                                  // folds away for FO>=64
#pragma unroll
      for (int i = 0; i < CPL; ++i) { kf[i] = 0.f; vf[i] = 0.f; }
    }
    eav = (lane < 32) ? ea[(size_t)eid * 32 + lane] : 0.f;
  };

  auto update = [&](const float* kf, const float* vf, float eav) {
    float part = qe * eav;
#pragma unroll
    for (int i = 0; i < CPL; ++i) part += q[i] * kf[i];
    float alpha = wave_sum(part) * scaleA;
    float mnew = fmaxf(m, alpha);
    float sc = __expf(m - mnew);   // exp(-inf)=0 on first edge
    float w = __expf(alpha - mnew);
    ssum = ssum * sc + w;
#pragma unroll
    for (int i = 0; i < CPL; ++i) vacc[i] = vacc[i] * sc + w * vf[i];
    wacc = wacc * sc + w * eav;
    m = mnew;
  };

  int p = start;
  for (; p + 4 <= end; p += 4) {
    int srcs[4], eids[4];
#pragma unroll
    for (int u = 0; u < 4; ++u) { srcs[u] = csr_src[p + u]; eids[u] = csr_eid[p + u]; }
    float kf[4][CPL], vf[4][CPL], eav[4];
#pragma unroll
    for (int u = 0; u < 4; ++u) gather(srcs[u], eids[u], kf[u], vf[u], eav[u]);
#pragma unroll
    for (int u = 0; u < 4; ++u) update(kf[u], vf[u], eav[u]);
  }
  for (; p < end; ++p) {
    float kf[CPL], vf[CPL], eav;
    gather(csr_src[p], csr_eid[p], kf, vf, eav);
    update(kf, vf, eav);
  }

  float inv = (ssum > 0.f) ? 1.0f / ssum : 0.f;
  float agg[CPL];
#pragma unroll
  for (int i = 0; i < CPL; ++i) agg[i] = vacc[i];
  // fold edge-attr contribution: agg[c] += sum_j wacc[j] * We[j][c]
#pragma unroll
  for (int j = 0; j < 32; ++j) {
    float wj = __shfl(wacc, j, 64);
    if (act) {
#pragma unroll
      for (int i = 0; i < CPL; ++i) agg[i] += wj * We[(size_t)j * FO + cbase + i];
    }
  }
  float hv[CPL];
#pragma unroll
  for (int i = 0; i < CPL; ++i) {
    float s = act ? (float)fq[3 * FO + cbase + i] : 0.f;
    hv[i] = fmaxf(agg[i] * inv + s, 0.f);
  }
  if constexpr (!FINAL) {
    if (act) {
#pragma unroll
      for (int i = 0; i < CPL; ++i) h_out[(size_t)node * FO + cbase + i] = (bf16)hv[i];
    }
  } else {
    float part2 = (lane < 32) ? hv[0] * Wc[lane] : 0.f;
    float s2 = wave_sum(part2);
    if (lane == 0) out[node] = s2 + bc[0];   // f32 output
  }
}

// ---------------- launch ----------------

extern "C" void kernel_launch(void* const* d_in, const int* in_sizes, int n_in,
                              void* d_out, int out_size, void* d_ws, size_t ws_size,
                              hipStream_t stream) {
  (void)in_sizes; (void)n_in; (void)out_size; (void)ws_size;
  const float* x = (const float*)d_in[0];
  const int* ei = (const int*)d_in[1];
  const float* ea = (const float*)d_in[2];
  const float *Wq1 = (const float*)d_in[3], *bq1 = (const float*)d_in[4];
  const float *Wk1 = (const float*)d_in[5], *bk1 = (const float*)d_in[6];
  const float *Wv1 = (const float*)d_in[7], *bv1 = (const float*)d_in[8];
  const float *We1 = (const float*)d_in[9];
  const float *Ws1 = (const float*)d_in[10], *bs1 = (const float*)d_in[11];
  const float *Wq2 = (const float*)d_in[12], *bq2 = (const float*)d_in[13];
  const float *Wk2 = (const float*)d_in[14], *bk2 = (const float*)d_in[15];
  const float *Wv2 = (const float*)d_in[16], *bv2 = (const float*)d_in[17];
  const float *We2 = (const float*)d_in[18];
  const float *Ws2 = (const float*)d_in[19], *bs2 = (const float*)d_in[20];
  const float *Wq3 = (const float*)d_in[21], *bq3 = (const float*)d_in[22];
  const float *Wk3 = (const float*)d_in[23], *bk3 = (const float*)d_in[24];
  const float *Wv3 = (const float*)d_in[25], *bv3 = (const float*)d_in[26];
  const float *We3 = (const float*)d_in[27];
  const float *Ws3 = (const float*)d_in[28], *bs3 = (const float*)d_in[29];
  const float *Wc = (const float*)d_in[30], *bc = (const float*)d_in[31];

  char* ws = (char*)d_ws;
  size_t off = 0;
  auto alloc = [&](size_t bytes) -> void* {
    void* p = ws + off;
    off = (off + bytes + 255) & ~(size_t)255;
    return p;
  };
  // Total ~74.6 MB (same scale as the known-safe R6/R7 plans).
  bf16* h       = (bf16*)alloc((size_t)N_NODES * 128 * 2);
  int* counts   = (int*)alloc((N_NODES + 1) * 4);
  int* row_ptr  = (int*)alloc((N_NODES + 1) * 4);
  int* cursor   = (int*)alloc((N_NODES + 1) * 4);
  int* csr_src  = (int*)alloc((size_t)N_EDGES * 4);
  int* csr_eid  = (int*)alloc((size_t)N_EDGES * 4);
  int* flags    = (int*)alloc(256);
  bf16* Wt      = (bf16*)alloc(544 * 128 * 2);
  float* bias   = (float*)alloc(544 * 4);
  bf16* feat    = (bf16*)alloc((size_t)N_NODES * 544 * 2);

  // index-width detection + CSR build (shared by all 3 layers)
  k_detect<<<1, 1, 0, stream>>>(ei, flags);
  k_zero<<<(N_NODES + 256) / 256, 256, 0, stream>>>(counts, N_NODES + 1);
  k_hist<<<(N_EDGES + 255) / 256, 256, 0, stream>>>(ei, flags, counts);
  k_scan<<<1, 1024, 0, stream>>>(counts, row_ptr, cursor);
  k_scatter<<<(N_EDGES + 255) / 256, 256, 0, stream>>>(ei, flags, cursor, csr_src, csr_eid);

  // Layer 1: FI=128, FO=128, NT=544
  k_prep<128, 128><<<544, 128, 0, stream>>>(Wq1, bq1, Wk1, bk1, Wv1, bv1, We1, Ws1, bs1,
                                            Wt, bias);
  {
    dim3 g((544 + 63) / 64, (N_NODES + 63) / 64);
    k_gemm_mfma<128, 128, true><<<g, 256, 0, stream>>>(x, Wt, bias, feat);
  }
  k_edge<128, false><<<N_NODES / 4, 256, 0, stream>>>(feat, ea, row_ptr, csr_src, csr_eid,
                                                      We1, h, nullptr, nullptr, nullptr);

  // Layer 2: FI=128, FO=64, NT=288
  k_prep<128, 64><<<288, 128, 0, stream>>>(Wq2, bq2, Wk2, bk2, Wv2, bv2, We2, Ws2, bs2,
                                           Wt, bias);
  {
    dim3 g((288 + 63) / 64, (N_NODES + 63) / 64);
    k_gemm_mfma<128, 64, false><<<g, 256, 0, stream>>>(h, Wt, bias, feat);
  }
  k_edge<64, false><<<N_NODES / 4, 256, 0, stream>>>(feat, ea, row_ptr, csr_src, csr_eid,
                                                     We2, h, nullptr, nullptr, nullptr);

  // Layer 3: FI=64, FO=32, NT=160
  k_prep<64, 32><<<160, 64, 0, stream>>>(Wq3, bq3, Wk3, bk3, Wv3, bv3, We3, Ws3, bs3,
                                         Wt, bias);
  {
    dim3 g((160 + 63) / 64, (N_NODES + 63) / 64);
    k_gemm_mfma<64, 32, false><<<g, 256, 0, stream>>>(h, Wt, bias, feat);
  }
  k_edge<32, true><<<N_NODES / 4, 256, 0, stream>>>(feat, ea, row_ptr, csr_src, csr_eid,
                                                    We3, nullptr, Wc, bc, (float*)d_out);
}